// Round 1
// baseline (248.230 us; speedup 1.0000x reference)
//
#include <hip/hip_runtime.h>

#define NV 50000
#define TT 8192
#define SS 16
#define DD 64
#define LEAKY 0.001f
#define PERMS (3*TT)      // 24576
#define WPB 4             // waves per block
#define PPW 12            // perms per wave
#define NBLK (PERMS/(WPB*PPW))  // 512
#define HSTR 68           // padded h row stride (floats)

__device__ __forceinline__ void wave_sync() {
  asm volatile("s_waitcnt lgkmcnt(0)" ::: "memory");
}

__global__ __launch_bounds__(WPB*64)
void tetra_mlp_kernel(const float* __restrict__ coords,
                      const int*   __restrict__ tetras,
                      const float* __restrict__ encoded,
                      const float* __restrict__ tvec,
                      const float* __restrict__ W1, const float* __restrict__ b1,
                      const float* __restrict__ W2, const float* __restrict__ b2,
                      const float* __restrict__ W3, const float* __restrict__ b3,
                      const float* __restrict__ W4, const float* __restrict__ b4,
                      float* __restrict__ answer)
{
  __shared__ float w2s[DD*DD];
  __shared__ float w3s[DD*DD];
  __shared__ float w4s[DD*2];
  __shared__ float tss[SS];
  __shared__ float encs[WPB][4*DD];
  __shared__ float hs[WPB][SS*HSTR];
  __shared__ float crs[WPB][SS*4];
  __shared__ float oas[WPB][SS*2];
  __shared__ float dls[WPB][SS*2];

  const int tid = threadIdx.x;
  for (int i = tid; i < DD*DD; i += WPB*64) { w2s[i] = W2[i]; w3s[i] = W3[i]; }
  if (tid < DD*2) w4s[tid] = W4[tid];
  if (tid < SS)   tss[tid] = tvec[tid];
  __syncthreads();

  const int wv   = tid >> 6;
  const int lane = tid & 63;

  // per-lane constants hoisted across all perms
  const float b1l = b1[lane];
  const float b2l = b2[lane];
  const float b3l = b3[lane];
  const float w1t = W1[256*DD + lane];
  const float w1o = W1[257*DD + lane];
  const float w1a = W1[258*DD + lane];
  const float b40 = b4[0], b41 = b4[1];

  const int permBase = (blockIdx.x * WPB + wv) * PPW;

  for (int pi = 0; pi < PPW; ++pi) {
    const int perm = permBase + pi;
    const int tet  = perm & (TT - 1);
    const int v    = perm >> 13;
    const int* tp  = tetras + tet * 5;
    const int i0 = tp[0], i1 = tp[1], i2 = tp[2], i3 = tp[3];
    const float sgn = (float)tp[4];
    int a = i0, b, c, d;
    if (v == 0)      { b = i1; c = i2; d = i3; }   // (0,1,2,3)
    else if (v == 1) { b = i3; c = i1; d = i2; }   // (0,3,1,2)
    else             { b = i2; c = i3; d = i1; }   // (0,2,3,1)

    // stage encoded rows (permuted order) into LDS
    encs[wv][0*DD + lane] = encoded[(size_t)a*DD + lane];
    encs[wv][1*DD + lane] = encoded[(size_t)b*DD + lane];
    encs[wv][2*DD + lane] = encoded[(size_t)c*DD + lane];
    encs[wv][3*DD + lane] = encoded[(size_t)d*DD + lane];

    // geometry: one s per lane (lanes 0..15)
    if (lane < SS) {
      const int s = lane;
      const float* pa = coords + ((size_t)a*SS + s)*3;
      const float* pb = coords + ((size_t)b*SS + s)*3;
      const float* pc = coords + ((size_t)c*SS + s)*3;
      const float* pd = coords + ((size_t)d*SS + s)*3;
      const float ax = pa[0], ay = pa[1], az = pa[2];
      const float v0x = pb[0]-ax, v0y = pb[1]-ay, v0z = pb[2]-az;
      const float v1x = pc[0]-ax, v1y = pc[1]-ay, v1z = pc[2]-az;
      const float v2x = pd[0]-ax, v2y = pd[1]-ay, v2z = pd[2]-az;
      float cx = (v1y*v2z - v1z*v2y) * sgn;
      float cy = (v1z*v2x - v1x*v2z) * sgn;
      float cz = (v1x*v2y - v1y*v2x) * sgn;
      const float rc = rsqrtf(cx*cx + cy*cy + cz*cz);
      cx *= rc; cy *= rc; cz *= rc;
      float sx = v1x+v2x, sy = v1y+v2y, sz = v1z+v2z;
      const float rs = rsqrtf(sx*sx + sy*sy + sz*sz);
      sx *= rs; sy *= rs; sz *= rs;
      const float outv  =  cx*v0x + cy*v0y + cz*v0z;
      const float along = -(sx*v0x + sy*v0y + sz*v0z);
      crs[wv][s*4+0] = cx; crs[wv][s*4+1] = cy; crs[wv][s*4+2] = cz;
      oas[wv][s*2+0] = outv  * 0.25f;
      oas[wv][s*2+1] = along * 0.25f;
    }
    wave_sync();

    // base1[j] = b1 + enc(256) @ W1[0:256, j]  (s-independent!)
    float base = b1l;
    const float* w1p = W1 + lane;
    #pragma unroll 4
    for (int k4 = 0; k4 < DD; ++k4) {
      const float4 ev = *(const float4*)&encs[wv][k4*4];
      base = fmaf(ev.x, w1p[(k4*4+0)*DD], base);
      base = fmaf(ev.y, w1p[(k4*4+1)*DD], base);
      base = fmaf(ev.z, w1p[(k4*4+2)*DD], base);
      base = fmaf(ev.w, w1p[(k4*4+3)*DD], base);
    }

    // h1 per s: add the 3 varying features, LeakyReLU, stash in LDS
    #pragma unroll
    for (int s = 0; s < SS; ++s) {
      float x = base + tss[s]*w1t + oas[wv][s*2]*w1o + oas[wv][s*2+1]*w1a;
      hs[wv][s*HSTR + lane] = (x >= 0.f) ? x : LEAKY*x;
    }
    wave_sync();

    // layer 2: acc[s] = b2 + h1[s,:] @ W2[:, lane]
    float acc[SS];
    #pragma unroll
    for (int s = 0; s < SS; ++s) acc[s] = b2l;
    for (int k4 = 0; k4 < DD/4; ++k4) {
      const float wa = w2s[(k4*4+0)*DD + lane];
      const float wb = w2s[(k4*4+1)*DD + lane];
      const float wc = w2s[(k4*4+2)*DD + lane];
      const float wd = w2s[(k4*4+3)*DD + lane];
      #pragma unroll
      for (int s = 0; s < SS; ++s) {
        const float4 hv = *(const float4*)&hs[wv][s*HSTR + k4*4];
        acc[s] = fmaf(hv.x, wa, fmaf(hv.y, wb, fmaf(hv.z, wc, fmaf(hv.w, wd, acc[s]))));
      }
    }
    wave_sync();
    #pragma unroll
    for (int s = 0; s < SS; ++s) {
      const float x = acc[s];
      hs[wv][s*HSTR + lane] = (x >= 0.f) ? x : LEAKY*x;
    }
    wave_sync();

    // layer 3
    #pragma unroll
    for (int s = 0; s < SS; ++s) acc[s] = b3l;
    for (int k4 = 0; k4 < DD/4; ++k4) {
      const float wa = w3s[(k4*4+0)*DD + lane];
      const float wb = w3s[(k4*4+1)*DD + lane];
      const float wc = w3s[(k4*4+2)*DD + lane];
      const float wd = w3s[(k4*4+3)*DD + lane];
      #pragma unroll
      for (int s = 0; s < SS; ++s) {
        const float4 hv = *(const float4*)&hs[wv][s*HSTR + k4*4];
        acc[s] = fmaf(hv.x, wa, fmaf(hv.y, wb, fmaf(hv.z, wc, fmaf(hv.w, wd, acc[s]))));
      }
    }
    wave_sync();
    #pragma unroll
    for (int s = 0; s < SS; ++s) {
      const float x = acc[s];
      hs[wv][s*HSTR + lane] = (x >= 0.f) ? x : LEAKY*x;
    }
    wave_sync();

    // layer 4: delta[s][o], one (s,o) pair per lane (lanes 0..31)
    if (lane < 32) {
      const int s = lane >> 1;
      const int o = lane & 1;
      float accd = o ? b41 : b40;
      #pragma unroll 4
      for (int k4 = 0; k4 < DD/4; ++k4) {
        const float4 hv = *(const float4*)&hs[wv][s*HSTR + k4*4];
        accd = fmaf(hv.x, w4s[(k4*4+0)*2+o],
               fmaf(hv.y, w4s[(k4*4+1)*2+o],
               fmaf(hv.z, w4s[(k4*4+2)*2+o],
               fmaf(hv.w, w4s[(k4*4+3)*2+o], accd))));
      }
      dls[wv][s*2+o] = accd;
    }
    wave_sync();

    // scatter: 16 s * 2 targets * 3 comps = 96 atomics
    #pragma unroll
    for (int r = 0; r < 2; ++r) {
      const int e = lane + r*64;
      if (e < SS*6) {
        const int s    = e / 6;
        const int k    = e - s*6;
        const int hi   = (k >= 3) ? 1 : 0;
        const int comp = k - hi*3;
        const float val = (hi ? 0.25f : -0.25f) * dls[wv][s*2+hi] * crs[wv][s*4+comp];
        const int tgt = hi ? b : a;
        unsafeAtomicAdd(answer + ((size_t)tgt*SS + s)*3 + comp, val);
      }
    }
    wave_sync();
  }
}

extern "C" void kernel_launch(void* const* d_in, const int* in_sizes, int n_in,
                              void* d_out, int out_size, void* d_ws, size_t ws_size,
                              hipStream_t stream) {
  const float* coords  = (const float*)d_in[0];
  const int*   tetras  = (const int*)d_in[1];
  const float* encoded = (const float*)d_in[2];
  const float* tvec    = (const float*)d_in[3];
  const float* answer  = (const float*)d_in[4];
  const float* W1 = (const float*)d_in[5];
  const float* b1 = (const float*)d_in[6];
  const float* W2 = (const float*)d_in[7];
  const float* b2 = (const float*)d_in[8];
  const float* W3 = (const float*)d_in[9];
  const float* b3 = (const float*)d_in[10];
  const float* W4 = (const float*)d_in[11];
  const float* b4 = (const float*)d_in[12];
  float* out = (float*)d_out;

  hipMemcpyAsync(out, answer, sizeof(float)*(size_t)out_size,
                 hipMemcpyDeviceToDevice, stream);
  tetra_mlp_kernel<<<NBLK, WPB*64, 0, stream>>>(coords, tetras, encoded, tvec,
                                                W1, b1, W2, b2, W3, b3, W4, b4, out);
}

// Round 2
// 48.435 us; speedup vs baseline: 5.1250x; 5.1250x over previous
//
#include <hip/hip_runtime.h>

#define TT 8192
#define SS 16
#define DD 64
#define LEAKY 0.001f
#define PERMS (3*TT)            // 24576
#define WPB 4                   // waves per block
#define PPW 12                  // perms per wave (batch)
#define NBLK (PERMS/(WPB*PPW))  // 512

typedef short  short8 __attribute__((ext_vector_type(8)));
typedef __bf16 bf16x8 __attribute__((ext_vector_type(8)));
typedef float  f32x4  __attribute__((ext_vector_type(4)));

union FragU { short8 s; bf16x8 b; };

__device__ __forceinline__ void wave_sync() {
  asm volatile("s_waitcnt lgkmcnt(0)" ::: "memory");
}
__device__ __forceinline__ short f2bf_rne(float x) {
  unsigned u = __builtin_bit_cast(unsigned, x);
  return (short)((u + 0x7FFFu + ((u >> 16) & 1u)) >> 16);
}
__device__ __forceinline__ short f2bf_fast(float x) {
  unsigned u = __builtin_bit_cast(unsigned, x);
  return (short)((u + 0x8000u) >> 16);
}
__device__ __forceinline__ float bf2f(short v) {
  return __builtin_bit_cast(float, ((unsigned)(unsigned short)v) << 16);
}
__device__ __forceinline__ float lrelu(float x) { return x >= 0.f ? x : LEAKY * x; }

__global__ __launch_bounds__(WPB*64)
void tetra_mlp_kernel(const float* __restrict__ coords,
                      const int*   __restrict__ tetras,
                      const float* __restrict__ encoded,
                      const float* __restrict__ tvec,
                      const float* __restrict__ W1, const float* __restrict__ b1,
                      const float* __restrict__ W2, const float* __restrict__ b2,
                      const float* __restrict__ W3, const float* __restrict__ b3,
                      const float* __restrict__ W4, const float* __restrict__ b4,
                      float* __restrict__ answer)
{
  // block-shared weight fragments (built once)
  __shared__ __align__(16) short w2f[8][64][8];     // 8192 B
  __shared__ __align__(16) short w3f[8][64][8];     // 8192 B
  __shared__ __align__(16) float w4cols[DD][2];     // 512 B
  __shared__ __align__(16) float w1r[3][DD];        // 768 B (W1 rows 256..258)
  // per-wave scratch
  __shared__ int   idxs_[WPB][PPW*5];               // 960 B
  __shared__ __align__(16) short bases_[WPB][PPW*DD]; // 6144 B (bf16)
  __shared__ __align__(16) short hs_[WPB][1024];    // 8192 B (swizzled h buffer)
  __shared__ short crs_[WPB][4*SS*3];               // 1536 B (bf16 cross)
  __shared__ __align__(4) unsigned short oas_[WPB][4*SS*2]; // 1024 B (bf16 out/along)
  __shared__ float dls_[WPB][SS*2];                 // 512 B

  const int tid = threadIdx.x;

  // ---- build W2/W3 fragments (frag-major, lane-contiguous) ----
  for (int e = tid; e < 8*64; e += WPB*64) {
    const int f = e >> 6, ln = e & 63;
    const int kg2 = ln >> 4, n2 = ln & 15;
    const int ks = f >> 2, nt = f & 3;
    const int base = (ks*32 + kg2*8)*DD + nt*16 + n2;
    #pragma unroll
    for (int j = 0; j < 8; ++j) {
      w2f[f][ln][j] = f2bf_rne(W2[base + j*DD]);
      w3f[f][ln][j] = f2bf_rne(W3[base + j*DD]);
    }
  }
  if (tid < DD*2) w4cols[tid >> 1][tid & 1] = W4[tid];
  if (tid < 3*DD) w1r[tid >> 6][tid & 63] = W1[256*DD + tid];
  __syncthreads();

  const int wv = tid >> 6, lane = tid & 63;
  const int kg = lane >> 4, n16 = lane & 15;
  int*   idxw = idxs_[wv];
  short* basw = bases_[wv];
  short* hsw  = hs_[wv];
  short* crw  = crs_[wv];
  unsigned short* oaw = oas_[wv];
  float* dlw  = dls_[wv];

  const float ts_l = tvec[n16];
  float b1v[4], b2v[4], b3v[4];
  #pragma unroll
  for (int nt = 0; nt < 4; ++nt) {
    b1v[nt] = b1[nt*16 + n16];
    b2v[nt] = b2[nt*16 + n16];
    b3v[nt] = b3[nt*16 + n16];
  }
  const float b40 = b4[0], b41 = b4[1];

  const int permBase = (blockIdx.x*WPB + wv)*PPW;

  // ---- batch init: per-perm vertex indices ----
  if (lane < PPW) {
    const int perm = permBase + lane;
    const int tet = perm & (TT-1), v = perm >> 13;
    const int* tp = tetras + tet*5;
    const int i0 = tp[0], i1 = tp[1], i2 = tp[2], i3 = tp[3], sg = tp[4];
    int b, c, d;
    if (v == 0)      { b = i1; c = i2; d = i3; }
    else if (v == 1) { b = i3; c = i1; d = i2; }
    else             { b = i2; c = i3; d = i1; }
    int* ip = &idxw[lane*5];
    ip[0] = i0; ip[1] = b; ip[2] = c; ip[3] = d; ip[4] = sg;
  }
  wave_sync();

  // ---- base = b1 + enc(256) @ W1[0:256]  for 12 perms via MFMA ----
  {
    f32x4 bD[4];
    #pragma unroll
    for (int nt = 0; nt < 4; ++nt) bD[nt] = (f32x4){b1v[nt], b1v[nt], b1v[nt], b1v[nt]};
    #pragma unroll
    for (int r = 0; r < 4; ++r) {
      #pragma unroll
      for (int ks = 0; ks < 2; ++ks) {
        FragU af;
        if (n16 < PPW) {
          const float* ep = encoded + (size_t)idxw[n16*5 + r]*DD + ks*32 + kg*8;
          const float4 e0 = *(const float4*)ep;
          const float4 e1 = *(const float4*)(ep + 4);
          af.s = (short8){f2bf_fast(e0.x), f2bf_fast(e0.y), f2bf_fast(e0.z), f2bf_fast(e0.w),
                          f2bf_fast(e1.x), f2bf_fast(e1.y), f2bf_fast(e1.z), f2bf_fast(e1.w)};
        } else {
          af.s = (short8){0,0,0,0,0,0,0,0};
        }
        const float* wp = W1 + (size_t)(r*64 + ks*32 + kg*8)*DD + n16;
        #pragma unroll
        for (int nt = 0; nt < 4; ++nt) {
          const float* wq = wp + nt*16;
          FragU bfr;
          #pragma unroll
          for (int j = 0; j < 8; ++j) bfr.s[j] = f2bf_rne(wq[j*DD]);
          bD[nt] = __builtin_amdgcn_mfma_f32_16x16x32_bf16(af.b, bfr.b, bD[nt], 0, 0, 0);
        }
      }
    }
    #pragma unroll
    for (int nt = 0; nt < 4; ++nt)
      #pragma unroll
      for (int r = 0; r < 4; ++r) {
        const int prow = kg*4 + r;           // D row = perm slot
        if (prow < PPW) basw[prow*DD + nt*16 + n16] = f2bf_fast(bD[nt][r]);
      }
  }
  wave_sync();

  // ---- per-perm pipeline ----
  #pragma unroll 1
  for (int pi = 0; pi < PPW; ++pi) {
    if ((pi & 3) == 0) {
      wave_sync();   // WAR: prior scatter reads of crs/oas complete (compile-order)
      // geometry for perms pi..pi+3, all 64 lanes: (kg -> perm, n16 -> s)
      const int pp = pi + kg;
      const int* ip = &idxw[pp*5];
      const int ga = ip[0], gb = ip[1], gc = ip[2], gd = ip[3];
      const float sg = (float)ip[4];
      const int s2 = n16;
      const float* pa = coords + ((size_t)ga*SS + s2)*3;
      const float* pb = coords + ((size_t)gb*SS + s2)*3;
      const float* pc = coords + ((size_t)gc*SS + s2)*3;
      const float* pd = coords + ((size_t)gd*SS + s2)*3;
      const float ax = pa[0], ay = pa[1], az = pa[2];
      const float v0x = pb[0]-ax, v0y = pb[1]-ay, v0z = pb[2]-az;
      const float v1x = pc[0]-ax, v1y = pc[1]-ay, v1z = pc[2]-az;
      const float v2x = pd[0]-ax, v2y = pd[1]-ay, v2z = pd[2]-az;
      float cx = (v1y*v2z - v1z*v2y)*sg;
      float cy = (v1z*v2x - v1x*v2z)*sg;
      float cz = (v1x*v2y - v1y*v2x)*sg;
      const float rc = rsqrtf(cx*cx + cy*cy + cz*cz);
      cx *= rc; cy *= rc; cz *= rc;
      float sx = v1x+v2x, sy = v1y+v2y, sz = v1z+v2z;
      const float rs = rsqrtf(sx*sx + sy*sy + sz*sz);
      sx *= rs; sy *= rs; sz *= rs;
      const float outv =   cx*v0x + cy*v0y + cz*v0z;
      const float alng = -(sx*v0x + sy*v0y + sz*v0z);
      const int oo = kg*SS + s2;
      crw[oo*3+0] = f2bf_rne(cx);
      crw[oo*3+1] = f2bf_rne(cy);
      crw[oo*3+2] = f2bf_rne(cz);
      oaw[oo*2+0] = (unsigned short)f2bf_rne(outv*0.25f);
      oaw[oo*2+1] = (unsigned short)f2bf_rne(alng*0.25f);
      wave_sync();
    }

    const int s = n16;

    // ---- build A1 = lrelu(base + t*w1t + out*w1o + along*w1a) as bf16 frags ----
    FragU a1[2];
    {
      const int ob = ((pi & 3)*SS + s)*2;
      const float o0 = bf2f((short)oaw[ob+0]);
      const float o1 = bf2f((short)oaw[ob+1]);
      #pragma unroll
      for (int ks = 0; ks < 2; ++ks) {
        const short8 bb = *(const short8*)&basw[pi*DD + ks*32 + kg*8];
        FragU af;
        #pragma unroll
        for (int q = 0; q < 2; ++q) {
          const int ko = ks*32 + kg*8 + q*4;
          const float4 wt = *(const float4*)&w1r[0][ko];
          const float4 wo = *(const float4*)&w1r[1][ko];
          const float4 wa = *(const float4*)&w1r[2][ko];
          #pragma unroll
          for (int j = 0; j < 4; ++j) {
            const float x = bf2f(bb[q*4+j]) + ts_l*wt[j] + o0*wo[j] + o1*wa[j];
            af.s[q*4+j] = f2bf_fast(lrelu(x));
          }
        }
        a1[ks] = af;
      }
    }

    // ---- layer 2 (MFMA) ----
    f32x4 d2[4];
    #pragma unroll
    for (int nt = 0; nt < 4; ++nt) d2[nt] = (f32x4){b2v[nt], b2v[nt], b2v[nt], b2v[nt]};
    #pragma unroll
    for (int ks = 0; ks < 2; ++ks)
      #pragma unroll
      for (int nt = 0; nt < 4; ++nt) {
        FragU wf; wf.s = *(const short8*)&w2f[ks*4+nt][lane][0];
        d2[nt] = __builtin_amdgcn_mfma_f32_16x16x32_bf16(a1[ks].b, wf.b, d2[nt], 0, 0, 0);
      }
    // h2 -> swizzled LDS (transpose)
    #pragma unroll
    for (int nt = 0; nt < 4; ++nt)
      #pragma unroll
      for (int r = 0; r < 4; ++r) {
        const int row = kg*4 + r;
        const int colB = nt*32 + n16*2;
        hsw[(row*128 + (colB ^ ((row & 7) << 4))) >> 1] = f2bf_fast(lrelu(d2[nt][r]));
      }
    wave_sync();

    // ---- layer 3 (MFMA) ----
    FragU a2[2];
    #pragma unroll
    for (int ks = 0; ks < 2; ++ks) {
      const int off = s*128 + ((ks*64 + kg*16) ^ ((s & 7) << 4));
      a2[ks].s = *(const short8*)((const char*)hsw + off);
    }
    f32x4 d3[4];
    #pragma unroll
    for (int nt = 0; nt < 4; ++nt) d3[nt] = (f32x4){b3v[nt], b3v[nt], b3v[nt], b3v[nt]};
    #pragma unroll
    for (int ks = 0; ks < 2; ++ks)
      #pragma unroll
      for (int nt = 0; nt < 4; ++nt) {
        FragU wf; wf.s = *(const short8*)&w3f[ks*4+nt][lane][0];
        d3[nt] = __builtin_amdgcn_mfma_f32_16x16x32_bf16(a2[ks].b, wf.b, d3[nt], 0, 0, 0);
      }
    #pragma unroll
    for (int nt = 0; nt < 4; ++nt)
      #pragma unroll
      for (int r = 0; r < 4; ++r) {
        const int row = kg*4 + r;
        const int colB = nt*32 + n16*2;
        hsw[(row*128 + (colB ^ ((row & 7) << 4))) >> 1] = f2bf_fast(lrelu(d3[nt][r]));
      }
    wave_sync();

    // ---- layer 4 (VALU + shuffle reduce): delta[s][0..1] ----
    float dd0 = 0.f, dd1 = 0.f;
    #pragma unroll
    for (int half = 0; half < 2; ++half) {
      const int off = s*128 + ((kg*32 + half*16) ^ ((s & 7) << 4));
      const short8 hv = *(const short8*)((const char*)hsw + off);
      #pragma unroll
      for (int j = 0; j < 8; ++j) {
        const int k = kg*16 + half*8 + j;
        const float h = bf2f(hv[j]);
        dd0 = fmaf(h, w4cols[k][0], dd0);
        dd1 = fmaf(h, w4cols[k][1], dd1);
      }
    }
    dd0 += __shfl_xor(dd0, 16, 64); dd0 += __shfl_xor(dd0, 32, 64);
    dd1 += __shfl_xor(dd1, 16, 64); dd1 += __shfl_xor(dd1, 32, 64);
    if (lane < SS) { dlw[lane*2+0] = dd0 + b40; dlw[lane*2+1] = dd1 + b41; }
    wave_sync();

    // ---- scatter: 96 atomics ----
    const int ta = idxw[pi*5+0], tb = idxw[pi*5+1];
    #pragma unroll
    for (int rr = 0; rr < 2; ++rr) {
      const int e = lane + rr*64;
      if (e < SS*6) {
        const int ss2 = e/6, k2 = e - ss2*6;
        const int hi = (k2 >= 3) ? 1 : 0, comp = k2 - hi*3;
        const float val = (hi ? 0.25f : -0.25f) * dlw[ss2*2+hi]
                        * bf2f(crw[((pi & 3)*SS + ss2)*3 + comp]);
        const int tgt = hi ? tb : ta;
        unsafeAtomicAdd(answer + ((size_t)tgt*SS + ss2)*3 + comp, val);
      }
    }
  }
}

extern "C" void kernel_launch(void* const* d_in, const int* in_sizes, int n_in,
                              void* d_out, int out_size, void* d_ws, size_t ws_size,
                              hipStream_t stream) {
  const float* coords  = (const float*)d_in[0];
  const int*   tetras  = (const int*)d_in[1];
  const float* encoded = (const float*)d_in[2];
  const float* tvec    = (const float*)d_in[3];
  const float* answer  = (const float*)d_in[4];
  const float* W1 = (const float*)d_in[5];
  const float* b1 = (const float*)d_in[6];
  const float* W2 = (const float*)d_in[7];
  const float* b2 = (const float*)d_in[8];
  const float* W3 = (const float*)d_in[9];
  const float* b3 = (const float*)d_in[10];
  const float* W4 = (const float*)d_in[11];
  const float* b4 = (const float*)d_in[12];
  float* out = (float*)d_out;

  hipMemcpyAsync(out, answer, sizeof(float)*(size_t)out_size,
                 hipMemcpyDeviceToDevice, stream);
  tetra_mlp_kernel<<<NBLK, WPB*64, 0, stream>>>(coords, tetras, encoded, tvec,
                                                W1, b1, W2, b2, W3, b3, W4, b4, out);
}